// Round 10
// baseline (524.185 us; speedup 1.0000x reference)
//
#include <hip/hip_runtime.h>
#include <hip/hip_bf16.h>

// RNN: B=1024, T=512, H=128, +4 autoregressive steps -> out (1024, 516)
// Round 21: 1-wave N-split (R18) + W PINNED INTO AGPRs. Evidence: R18
// (2380cy/step, full W) vs R19 (1580cy, half W) differ by exactly
// 16 frag-reloads x ~50cy -> base N-split = ~780cy/step + per-step W
// refetch in BOTH; R20's "+v" pin didn't move the allocator (VGPR stuck
// at 132). Fix: asm "+a" constraint forces W fragments into the AGPR
// file - a class the allocator isn't rationing - and gfx950 MFMA reads
// A-operands from AGPRs natively (ISA sec 10), so no per-use copies are
// required. 1 wave/block = zero barriers, zero exchange; unified file
// has room (128 AGPR + ~280 VGPR < 512 at 1 wave/SIMD).
// Also fixed vs R18: xs stride 513 (was 512 -> 983K bank conflicts);
// dec shfl pair issued BEFORE bfr pack (latency hides under pack VALU).
// Unit permutation (unchanged, R18-validated): row m of M-tile mt
// computes unit O(mt,m)=32*(mt&3)+8*(m>>2)+4*(mt>>2)+(m&3), so the C
// fragment at lane (q,n) IS the next step's B fragment (free repack).
// Kept: W/b/w0 pre-scaled by 2*log2e (acc = exp2 arg), phase-batched
// epilogue, v_cvt_pkrtz packing, static unrolls everywhere.

#define BB 1024
#define TT 512
#define HH 128
#define TOUT 516
#define BM 16          // batch rows per wave (= MFMA N)
#define XSTR 513       // xs stride (dwords) - coprime to 32 banks
#define TWOLOG2E 2.885390082f

typedef __attribute__((ext_vector_type(8))) _Float16 f16x8;
typedef __attribute__((ext_vector_type(4))) float f32x4;
typedef __attribute__((ext_vector_type(4))) unsigned int u32x4;

#define MFMA16(A_, B_, C_) __builtin_amdgcn_mfma_f32_16x16x32_f16(A_, B_, C_, 0, 0, 0)

__global__ void detect_dtype(const void* w, int* flag) {
    const int lane = threadIdx.x;  // 64 threads
    const __hip_bfloat16* p = (const __hip_bfloat16*)w;
    const float v0 = __bfloat162float(p[lane]);
    const float v1 = __bfloat162float(p[64 + lane]);
    const bool bad = !(fabsf(v0) < 100.0f) || !(fabsf(v1) < 100.0f);
    const unsigned long long m = __ballot(bad);
    if (lane == 0) *flag = (__popcll(m) > 4) ? 1 : 0;  // 1 => data is fp32
}

template <bool F32>
__device__ __forceinline__ float ldg(const void* p, int idx) {
    if (F32) return ((const float*)p)[idx];
    return __bfloat162float(((const __hip_bfloat16*)p)[idx]);
}

template <bool F32>
__device__ __forceinline__ void stg(void* p, int idx, float v) {
    if (F32) ((float*)p)[idx] = v;
    else     ((__hip_bfloat16*)p)[idx] = __float2bfloat16(v);
}

// Force a fragment into AGPRs (opaque to the allocator: cannot be
// rematerialized; MFMA consumes A-operands from AGPR natively on gfx950).
__device__ __forceinline__ void pina(f16x8& v) {
    u32x4 u = __builtin_bit_cast(u32x4, v);
    asm volatile("" : "+a"(u));
    v = __builtin_bit_cast(f16x8, u);
}
// Pin epilogue constants into VGPRs (opaque; blocks rematerialization).
__device__ __forceinline__ void pinv(f32x4& v) {
    asm volatile("" : "+v"(v));
}

// output-unit permutation: row m of M-tile mt computes unit O(mt, m)
__device__ __forceinline__ int unit_of(int mt, int m) {
    return 32 * (mt & 3) + 8 * (m >> 2) + 4 * (mt >> 2) + (m & 3);
}

template <bool F32>
__device__ void rnn_body(const void* __restrict__ xg, const void* __restrict__ h0,
                         const void* __restrict__ w0, const void* __restrict__ b0,
                         const void* __restrict__ W,  const void* __restrict__ bw,
                         const void* __restrict__ dw, const void* __restrict__ db,
                         void* __restrict__ out, float (*xs)[XSTR])
{
    const int tid  = threadIdx.x;     // 0..63, single wave per block
    const int q    = tid >> 4;        // 0..3 (k-subchunk / C row-quadrant)
    const int n    = tid & 15;        // batch col (B col / C col / A row)
    const int row0 = blockIdx.x * BM;

    // stage this wave's x rows into LDS (padded stride, conflict-free)
    for (int idx = tid; idx < BM * TT; idx += 64) {
        const int rr = idx >> 9, t2 = idx & (TT - 1);
        xs[rr][t2] = ldg<F32>(xg, (row0 + rr) * TT + t2);
    }

    // W fragments for ALL 8 M-tiles (A[m=n][k=32kf+8q+j] = 2log2e *
    // W[unit_of(mt,n)][k]); pinned into AGPRs (128 regs), loaded once.
    f16x8 wa[8][4];
    #pragma unroll
    for (int mt = 0; mt < 8; ++mt) {
        const int row = unit_of(mt, n);
        #pragma unroll
        for (int kf = 0; kf < 4; ++kf) {
            f16x8 fr;
            #pragma unroll
            for (int j = 0; j < 8; ++j)
                fr[j] = (_Float16)(TWOLOG2E * ldg<F32>(W, row * HH + 32 * kf + 8 * q + j));
            wa[mt][kf] = fr;
        }
    }
    #pragma unroll
    for (int mt = 0; mt < 8; ++mt) {
        #pragma unroll
        for (int kf = 0; kf < 4; ++kf) pina(wa[mt][kf]);
    }

    // epilogue constants per (mt, r): unit O(mt, 4q+r); pre-scaled; pinned
    f32x4 bsum[8], w0v[8], decv[8];
    #pragma unroll
    for (int mt = 0; mt < 8; ++mt) {
        #pragma unroll
        for (int r = 0; r < 4; ++r) {
            const int u = unit_of(mt, 4 * q + r);
            bsum[mt][r] = TWOLOG2E * (ldg<F32>(b0, u) + ldg<F32>(bw, u));
            w0v[mt][r]  = TWOLOG2E * ldg<F32>(w0, u);
            decv[mt][r] = ldg<F32>(dw, u);
        }
        pinv(bsum[mt]); pinv(w0v[mt]); pinv(decv[mt]);
    }
    const float dbv = ldg<F32>(db, 0);

    // initial B fragments from h0: bfr[kf] half j = h0[row0+n][32kf+8q+j]
    f16x8 bfr[4];
    #pragma unroll
    for (int kf = 0; kf < 4; ++kf) {
        f16x8 fr;
        #pragma unroll
        for (int j = 0; j < 8; ++j)
            fr[j] = (_Float16)ldg<F32>(h0, (row0 + n) * HH + 32 * kf + 8 * q + j);
        bfr[kf] = fr;
    }

    const int obase = (row0 + n) * TOUT;
    float xv = xs[n][0];

    // acc accumulates 2log2e*z; h = 1 - 2/(exp2(acc)+1)
    #pragma unroll 1
    for (int t = 0; t < TOUT; ++t) {
        // C init: bias + x*w0 (pre-scaled)
        f32x4 acc[8];
        #pragma unroll
        for (int mt = 0; mt < 8; ++mt) {
            #pragma unroll
            for (int r = 0; r < 4; ++r)
                acc[mt][r] = fmaf(xv, w0v[mt][r], bsum[mt][r]);
        }
        // 32 MFMAs: kf outer (8 independent chains of depth 4)
        #pragma unroll
        for (int kf = 0; kf < 4; ++kf) {
            #pragma unroll
            for (int mt = 0; mt < 8; ++mt)
                acc[mt] = MFMA16(wa[mt][kf], bfr[kf], acc[mt]);
        }
        // x prefetch for next step (broadcast read, conflict-free)
        float xnext = 0.0f;
        if (t < 511) xnext = xs[n][t + 1];
        // epilogue, phase-batched (trans ops pipeline)
        f32x4 ex[8], rc[8], hv[8];
        #pragma unroll
        for (int mt = 0; mt < 8; ++mt) {
            #pragma unroll
            for (int r = 0; r < 4; ++r) ex[mt][r] = __builtin_amdgcn_exp2f(acc[mt][r]);
        }
        #pragma unroll
        for (int mt = 0; mt < 8; ++mt) {
            #pragma unroll
            for (int r = 0; r < 4; ++r) rc[mt][r] = __builtin_amdgcn_rcpf(ex[mt][r] + 1.0f);
        }
        #pragma unroll
        for (int mt = 0; mt < 8; ++mt) {
            #pragma unroll
            for (int r = 0; r < 4; ++r) hv[mt][r] = fmaf(-2.0f, rc[mt][r], 1.0f);
        }
        // dec partial + shfl pair ISSUED EARLY (latency hides under pack)
        float p = 0.0f;
        #pragma unroll
        for (int mt = 0; mt < 8; ++mt) {
            #pragma unroll
            for (int r = 0; r < 4; ++r) p = fmaf(decv[mt][r], hv[mt][r], p);
        }
        p += __shfl_xor(p, 16);
        p += __shfl_xor(p, 32);
        // pack next B (free repack: C fragment == B fragment by unit perm)
        #pragma unroll
        for (int kf = 0; kf < 4; ++kf) {
            u32x4 w;
            w[0] = __builtin_bit_cast(unsigned, __builtin_amdgcn_cvt_pkrtz(hv[kf][0], hv[kf][1]));
            w[1] = __builtin_bit_cast(unsigned, __builtin_amdgcn_cvt_pkrtz(hv[kf][2], hv[kf][3]));
            w[2] = __builtin_bit_cast(unsigned, __builtin_amdgcn_cvt_pkrtz(hv[kf + 4][0], hv[kf + 4][1]));
            w[3] = __builtin_bit_cast(unsigned, __builtin_amdgcn_cvt_pkrtz(hv[kf + 4][2], hv[kf + 4][3]));
            bfr[kf] = __builtin_bit_cast(f16x8, w);
        }
        const float y = p + dbv;
        if (q == 0) stg<F32>(out, obase + t, y);
        // next x: sequence input for t<511, own y feedback for the tail
        xv = (t < 511) ? xnext : y;
    }
}

__global__ __launch_bounds__(64, 1)
void rnn_mfma(const void* __restrict__ xg, const void* __restrict__ h0,
              const void* __restrict__ w0, const void* __restrict__ b0,
              const void* __restrict__ W,  const void* __restrict__ bw,
              const void* __restrict__ dw, const void* __restrict__ db,
              void* __restrict__ out, const int* __restrict__ flag)
{
    __shared__ float xs[BM][XSTR];                          // 32.8 KB

    const int f = *(volatile const int*)flag;  // block-uniform
    if (f) rnn_body<true >(xg, h0, w0, b0, W, bw, dw, db, out, xs);
    else   rnn_body<false>(xg, h0, w0, b0, W, bw, dw, db, out, xs);
}

extern "C" void kernel_launch(void* const* d_in, const int* in_sizes, int n_in,
                              void* d_out, int out_size, void* d_ws, size_t ws_size,
                              hipStream_t stream) {
    int* flag = (int*)d_ws;
    detect_dtype<<<1, 64, 0, stream>>>(d_in[4], flag);  // probe fc_w
    rnn_mfma<<<BB / BM, 64, 0, stream>>>(d_in[0], d_in[1], d_in[2], d_in[3],
                                         d_in[4], d_in[5], d_in[6], d_in[7],
                                         d_out, flag);
}